// Round 3
// baseline (502.585 us; speedup 1.0000x reference)
//
#include <hip/hip_runtime.h>

constexpr int N  = 4096;   // H*W
constexpr int C  = 512;
constexpr int CK = 64;     // C/8
constexpr int B  = 4;

typedef __attribute__((ext_vector_type(8))) short short8;
typedef __attribute__((ext_vector_type(4))) float f32x4;

// ---------------------------------------------------------------------------
// Kernel 1 (fused): f = Wq @ x, g = Wk @ x computed in fp32, split to bf16
// hi/lo in-register, transposed through LDS, written directly as
// fT/gT [i][k] hi/lo.
// ---------------------------------------------------------------------------
__global__ __launch_bounds__(512, 1)
void proj_fgT(const float* __restrict__ x, const float* __restrict__ Wq,
              const float* __restrict__ Wk,
              ushort* __restrict__ fT_hi, ushort* __restrict__ fT_lo,
              ushort* __restrict__ gT_hi, ushort* __restrict__ gT_lo)
{
    int b  = blockIdx.y;
    int i0 = blockIdx.x * 64;
    __shared__ __align__(16) float  xs[16][64];
    __shared__ __align__(16) float  ws[16][132];
    __shared__ __align__(16) ushort oh[64][136];
    __shared__ __align__(16) ushort ol[64][136];
    int tid = threadIdx.x, ty = tid >> 4, tx = tid & 15;  // ty 0..31
    float acc[4][4] = {};   // rows k = ty*4+r (0..127), cols i = i0+tx*4+cl
    const float* xb = x + (size_t)b * C * N;

    for (int c0 = 0; c0 < C; c0 += 16) {
        if (tid < 256) {
            int cc = tid >> 4, col4 = (tid & 15) * 4;
            *(float4*)&xs[cc][col4] =
                *(const float4*)&xb[(size_t)(c0 + cc) * N + i0 + col4];
        }
        #pragma unroll
        for (int v = tid; v < 2048; v += 512) {
            int row = v >> 4, cc = v & 15;
            ws[cc][row] = (row < 64) ? Wq[row * C + c0 + cc]
                                     : Wk[(row - 64) * C + c0 + cc];
        }
        __syncthreads();
        #pragma unroll
        for (int cc = 0; cc < 16; ++cc) {
            float4 wa = *(const float4*)&ws[cc][ty * 4];
            float4 xa = *(const float4*)&xs[cc][tx * 4];
            float wr[4] = {wa.x, wa.y, wa.z, wa.w};
            float xc[4] = {xa.x, xa.y, xa.z, xa.w};
            #pragma unroll
            for (int r = 0; r < 4; ++r)
                #pragma unroll
                for (int cl = 0; cl < 4; ++cl)
                    acc[r][cl] += wr[r] * xc[cl];
        }
        __syncthreads();
    }

    #pragma unroll
    for (int r = 0; r < 4; ++r)
        #pragma unroll
        for (int cl = 0; cl < 4; ++cl) {
            float v = acc[r][cl];
            unsigned bits = __float_as_uint(v);
            unsigned hb   = bits & 0xFFFF0000u;
            float lof = v - __uint_as_float(hb);
            oh[tx * 4 + cl][ty * 4 + r] = (ushort)(hb >> 16);
            ol[tx * 4 + cl][ty * 4 + r] = (ushort)(__float_as_uint(lof) >> 16);
        }
    __syncthreads();

    int i = tid >> 3, kc = (tid & 7) * 8;   // 64 i rows x 8 k-chunks
    size_t ofs = ((size_t)b * N + i0 + i) * 64 + kc;
    *(uint4*)&fT_hi[ofs] = *(const uint4*)&oh[i][kc];
    *(uint4*)&fT_lo[ofs] = *(const uint4*)&ol[i][kc];
    *(uint4*)&gT_hi[ofs] = *(const uint4*)&oh[i][64 + kc];
    *(uint4*)&gT_lo[ofs] = *(const uint4*)&ol[i][64 + kc];
}

// ---------------------------------------------------------------------------
// Kernels 2/4: MFMA scores + exp, LDS-FREE register-streaming version.
// Block = 128 rows x 512-col chunk. A-fragments (wave's 32 rows, 32 VGPR)
// load once from global (L2) and stay in registers across 4 j-tiles of 128.
// B-fragments stream global->VGPR per tile (fT/gT are ~1 MB/batch =
// L2-resident). No __shared__, no __syncthreads anywhere.
// PASS=1: colsum via quad-shfl + atomic. PASS=2: beta write (scaled by
// inv colsum) + rowsum accumulated in registers across tiles, one
// shfl-reduce + atomic per block.
// ---------------------------------------------------------------------------
template <int PASS>
__global__ __launch_bounds__(256, 2)
void scores_pass(const ushort* __restrict__ fT_hi, const ushort* __restrict__ fT_lo,
                 const ushort* __restrict__ gT_hi, const ushort* __restrict__ gT_lo,
                 const float* __restrict__ inv_l, float* __restrict__ colsum,
                 float* __restrict__ beta, float* __restrict__ rowsum)
{
    constexpr int JCHUNK = 512;
    constexpr int NTILE  = JCHUNK / 128;   // 4 j-tiles per block
    int b = blockIdx.z, i0 = blockIdx.y * 128, jc0 = blockIdx.x * JCHUNK;
    int tid = threadIdx.x;
    int w = tid >> 6, lane = tid & 63, l15 = lane & 15, quad = lane >> 4;

    // A fragments: wave w owns rows i0 + w*32 .. +32, resident in registers.
    // Same lane->element mapping as the LDS version: row = tr*16 + l15,
    // k = ks*32 + quad*8 + e (8 contiguous).
    const ushort* fh = fT_hi + ((size_t)b * N + i0 + w * 32 + l15) * 64 + quad * 8;
    const ushort* fl = fT_lo + ((size_t)b * N + i0 + w * 32 + l15) * 64 + quad * 8;
    short8 a_hi[2][2], a_lo[2][2];   // [tr][ks]
    #pragma unroll
    for (int tr = 0; tr < 2; ++tr)
        #pragma unroll
        for (int ks = 0; ks < 2; ++ks) {
            a_hi[tr][ks] = *(const short8*)&fh[(size_t)(tr * 16) * 64 + ks * 32];
            a_lo[tr][ks] = *(const short8*)&fl[(size_t)(tr * 16) * 64 + ks * 32];
        }

    float rp[2][4] = {};   // PASS=2 rowsum accumulator across all tiles

    #pragma unroll 1
    for (int jt = 0; jt < NTILE; ++jt) {
        int j0 = jc0 + jt * 128;
        const ushort* gh = gT_hi + ((size_t)b * N + j0 + l15) * 64 + quad * 8;
        const ushort* gl = gT_lo + ((size_t)b * N + j0 + l15) * 64 + quad * 8;
        f32x4 acc[2][8] = {};

        #pragma unroll
        for (int ks = 0; ks < 2; ++ks) {
            #pragma unroll
            for (int tc = 0; tc < 8; ++tc) {
                short8 b_hi = *(const short8*)&gh[(size_t)(tc * 16) * 64 + ks * 32];
                short8 b_lo = *(const short8*)&gl[(size_t)(tc * 16) * 64 + ks * 32];
                #pragma unroll
                for (int tr = 0; tr < 2; ++tr) {
                    acc[tr][tc] = __builtin_amdgcn_mfma_f32_16x16x32_bf16(a_hi[tr][ks], b_hi, acc[tr][tc], 0, 0, 0);
                    acc[tr][tc] = __builtin_amdgcn_mfma_f32_16x16x32_bf16(a_hi[tr][ks], b_lo, acc[tr][tc], 0, 0, 0);
                    acc[tr][tc] = __builtin_amdgcn_mfma_f32_16x16x32_bf16(a_lo[tr][ks], b_hi, acc[tr][tc], 0, 0, 0);
                }
            }
        }

        if (PASS == 1) {
            #pragma unroll
            for (int tc = 0; tc < 8; ++tc) {
                float s = 0.f;
                #pragma unroll
                for (int tr = 0; tr < 2; ++tr)
                    #pragma unroll
                    for (int r = 0; r < 4; ++r)
                        s += __expf(acc[tr][tc][r] - 20.0f);
                // sum the 4 quads (same column j0+tc*16+l15 within this wave)
                s += __shfl_xor(s, 16);
                s += __shfl_xor(s, 32);
                if (lane < 16)
                    atomicAdd(&colsum[(size_t)b * N + j0 + tc * 16 + l15], s);
            }
        } else {
            float il[8];
            #pragma unroll
            for (int tc = 0; tc < 8; ++tc)
                il[tc] = inv_l[(size_t)b * N + j0 + tc * 16 + l15];
            float* pb = beta + (size_t)b * N * N;
            #pragma unroll
            for (int tr = 0; tr < 2; ++tr)
                #pragma unroll
                for (int tc = 0; tc < 8; ++tc) {
                    int j = j0 + tc * 16 + l15;
                    #pragma unroll
                    for (int r = 0; r < 4; ++r) {
                        int i = i0 + w * 32 + tr * 16 + quad * 4 + r;
                        float v = __expf(acc[tr][tc][r] - 20.0f) * il[tc];
                        rp[tr][r] += v;
                        pb[(size_t)i * N + j] = v;
                    }
                }
        }
    }

    if (PASS == 2) {
        #pragma unroll
        for (int tr = 0; tr < 2; ++tr)
            #pragma unroll
            for (int r = 0; r < 4; ++r) {
                float s = rp[tr][r];
                s += __shfl_xor(s, 1); s += __shfl_xor(s, 2);
                s += __shfl_xor(s, 4); s += __shfl_xor(s, 8);
                if (l15 == 0)
                    atomicAdd(&rowsum[(size_t)b * N + i0 + w * 32 + tr * 16 + quad * 4 + r], s);
            }
    }
}

// ---------------------------------------------------------------------------
// Kernel 3: in-place invert colsum
// ---------------------------------------------------------------------------
__global__ __launch_bounds__(256)
void invert_colsum(float* __restrict__ c)
{
    int t = blockIdx.x * 256 + threadIdx.x;
    c[t] = 1.0f / c[t];
}

// ---------------------------------------------------------------------------
// Kernel 5: meanx[b,c] = mean_i x; t[b,c] = sum_i x[b,c,i]*rowsum[b,i]
// ---------------------------------------------------------------------------
__global__ __launch_bounds__(256)
void reduce_xr(const float* __restrict__ x, const float* __restrict__ rowsum,
               float* __restrict__ meanx, float* __restrict__ tvec)
{
    int b = blockIdx.y, c = blockIdx.x, tid = threadIdx.x;
    const float* xr = x + ((size_t)b * C + c) * N;
    const float* rr = rowsum + (size_t)b * N;
    float sx = 0.f, st = 0.f;
    for (int base = 0; base < N; base += 1024) {
        int i = base + tid * 4;
        float4 xv = *(const float4*)&xr[i];
        float4 rv = *(const float4*)&rr[i];
        sx += xv.x + xv.y + xv.z + xv.w;
        st += xv.x * rv.x + xv.y * rv.y + xv.z * rv.z + xv.w * rv.w;
    }
    __shared__ float s1[256], s2[256];
    s1[tid] = sx; s2[tid] = st;
    __syncthreads();
    for (int s = 128; s > 0; s >>= 1) {
        if (tid < s) { s1[tid] += s1[tid + s]; s2[tid] += s2[tid + s]; }
        __syncthreads();
    }
    if (tid == 0) {
        meanx[b * C + c] = s1[0] * (1.0f / N);
        tvec [b * C + c] = s2[0];
    }
}

// ---------------------------------------------------------------------------
// Kernel 6: pooled[b,c] = meanx + (gamma/N) * sum_c' Wv[c,c'] * t[b,c']
// ---------------------------------------------------------------------------
__global__ __launch_bounds__(64)
void pooled_out(const float* __restrict__ Wv, const float* __restrict__ meanx,
                const float* __restrict__ tvec, const float* __restrict__ gamma,
                float* __restrict__ out)
{
    int b = blockIdx.y, c = blockIdx.x;
    const float* wr = Wv + (size_t)c * C;
    const float* t  = tvec + (size_t)b * C;
    float s = 0.f;
    for (int cc = threadIdx.x; cc < C; cc += 64) s += wr[cc] * t[cc];
    for (int off = 32; off > 0; off >>= 1) s += __shfl_down(s, off);
    if (threadIdx.x == 0)
        out[b * C + c] = meanx[b * C + c] + gamma[0] * (1.0f / N) * s;
}

// ---------------------------------------------------------------------------
extern "C" void kernel_launch(void* const* d_in, const int* in_sizes, int n_in,
                              void* d_out, int out_size, void* d_ws, size_t ws_size,
                              hipStream_t stream)
{
    const float* x     = (const float*)d_in[0];
    const float* Wq    = (const float*)d_in[1];
    const float* Wk    = (const float*)d_in[2];
    const float* Wv    = (const float*)d_in[3];
    const float* gamma = (const float*)d_in[4];
    float* out  = (float*)d_out;
    float* beta = out + (size_t)B * C;

    ushort* fT_hi = (ushort*)d_ws;                         // each B*N*64 ushort
    ushort* fT_lo = fT_hi + (size_t)B * N * 64;
    ushort* gT_hi = fT_lo + (size_t)B * N * 64;
    ushort* gT_lo = gT_hi + (size_t)B * N * 64;
    float*  colsum = (float*)(gT_lo + (size_t)B * N * 64); // B*N
    float*  rowsum = colsum + (size_t)B * N;               // B*N
    float*  meanx  = rowsum + (size_t)B * N;               // B*C
    float*  tvec   = meanx + (size_t)B * C;                // B*C

    hipMemsetAsync(colsum, 0, 2 * (size_t)B * N * sizeof(float), stream);

    proj_fgT       <<<dim3(N / 64, B),           512, 0, stream>>>(x, Wq, Wk, fT_hi, fT_lo, gT_hi, gT_lo);
    scores_pass<1> <<<dim3(N / 512, N / 128, B), 256, 0, stream>>>(fT_hi, fT_lo, gT_hi, gT_lo,
                                                                   colsum, colsum, beta, rowsum);
    invert_colsum  <<<dim3(B * N / 256),         256, 0, stream>>>(colsum);
    scores_pass<2> <<<dim3(N / 512, N / 128, B), 256, 0, stream>>>(fT_hi, fT_lo, gT_hi, gT_lo,
                                                                   colsum, colsum, beta, rowsum);
    reduce_xr      <<<dim3(C, B),                256, 0, stream>>>(x, rowsum, meanx, tvec);
    pooled_out     <<<dim3(C, B),                 64, 0, stream>>>(Wv, meanx, tvec, gamma, out);
}

// Round 4
// 466.208 us; speedup vs baseline: 1.0780x; 1.0780x over previous
//
#include <hip/hip_runtime.h>

constexpr int N  = 4096;   // H*W
constexpr int C  = 512;
constexpr int CK = 64;     // C/8
constexpr int B  = 4;

typedef __attribute__((ext_vector_type(8))) short short8;
typedef __attribute__((ext_vector_type(4))) float f32x4;

// ---------------------------------------------------------------------------
// Kernel 1 (fused): f = Wq @ x, g = Wk @ x computed in fp32, split to bf16
// hi/lo in-register, transposed through LDS, written directly as
// fT/gT [i][k] hi/lo.
// ---------------------------------------------------------------------------
__global__ __launch_bounds__(512, 1)
void proj_fgT(const float* __restrict__ x, const float* __restrict__ Wq,
              const float* __restrict__ Wk,
              ushort* __restrict__ fT_hi, ushort* __restrict__ fT_lo,
              ushort* __restrict__ gT_hi, ushort* __restrict__ gT_lo)
{
    int b  = blockIdx.y;
    int i0 = blockIdx.x * 64;
    __shared__ __align__(16) float  xs[16][64];
    __shared__ __align__(16) float  ws[16][132];
    __shared__ __align__(16) ushort oh[64][136];
    __shared__ __align__(16) ushort ol[64][136];
    int tid = threadIdx.x, ty = tid >> 4, tx = tid & 15;  // ty 0..31
    float acc[4][4] = {};   // rows k = ty*4+r (0..127), cols i = i0+tx*4+cl
    const float* xb = x + (size_t)b * C * N;

    for (int c0 = 0; c0 < C; c0 += 16) {
        if (tid < 256) {
            int cc = tid >> 4, col4 = (tid & 15) * 4;
            *(float4*)&xs[cc][col4] =
                *(const float4*)&xb[(size_t)(c0 + cc) * N + i0 + col4];
        }
        #pragma unroll
        for (int v = tid; v < 2048; v += 512) {
            int row = v >> 4, cc = v & 15;
            ws[cc][row] = (row < 64) ? Wq[row * C + c0 + cc]
                                     : Wk[(row - 64) * C + c0 + cc];
        }
        __syncthreads();
        #pragma unroll
        for (int cc = 0; cc < 16; ++cc) {
            float4 wa = *(const float4*)&ws[cc][ty * 4];
            float4 xa = *(const float4*)&xs[cc][tx * 4];
            float wr[4] = {wa.x, wa.y, wa.z, wa.w};
            float xc[4] = {xa.x, xa.y, xa.z, xa.w};
            #pragma unroll
            for (int r = 0; r < 4; ++r)
                #pragma unroll
                for (int cl = 0; cl < 4; ++cl)
                    acc[r][cl] += wr[r] * xc[cl];
        }
        __syncthreads();
    }

    #pragma unroll
    for (int r = 0; r < 4; ++r)
        #pragma unroll
        for (int cl = 0; cl < 4; ++cl) {
            float v = acc[r][cl];
            unsigned bits = __float_as_uint(v);
            unsigned hb   = bits & 0xFFFF0000u;
            float lof = v - __uint_as_float(hb);
            oh[tx * 4 + cl][ty * 4 + r] = (ushort)(hb >> 16);
            ol[tx * 4 + cl][ty * 4 + r] = (ushort)(__float_as_uint(lof) >> 16);
        }
    __syncthreads();

    int i = tid >> 3, kc = (tid & 7) * 8;   // 64 i rows x 8 k-chunks
    size_t ofs = ((size_t)b * N + i0 + i) * 64 + kc;
    *(uint4*)&fT_hi[ofs] = *(const uint4*)&oh[i][kc];
    *(uint4*)&fT_lo[ofs] = *(const uint4*)&ol[i][kc];
    *(uint4*)&gT_hi[ofs] = *(const uint4*)&oh[i][64 + kc];
    *(uint4*)&gT_lo[ofs] = *(const uint4*)&ol[i][64 + kc];
}

// ---------------------------------------------------------------------------
// Kernel 2: SINGLE scores pass (round-1 verified LDS-staged structure).
// Computes exp(s-20) once, stores UNNORMALIZED values to beta, and
// accumulates colsum via LDS reduction + atomics. Normalization by
// inv colsum is deferred to the streaming normalize_rows kernel.
// ---------------------------------------------------------------------------
__global__ __launch_bounds__(256, 2)
void scores_exp(const ushort* __restrict__ fT_hi, const ushort* __restrict__ fT_lo,
                const ushort* __restrict__ gT_hi, const ushort* __restrict__ gT_lo,
                float* __restrict__ colsum, float* __restrict__ beta)
{
    int b = blockIdx.z, i0 = blockIdx.y * 128, j0 = blockIdx.x * 128;
    __shared__ ushort sm[4][128][72];   // 73.7 KB, pad 8 -> 2-way-free banks
    int tid = threadIdx.x;

    const ushort* fh = fT_hi + ((size_t)b * N + i0) * 64;
    const ushort* fl = fT_lo + ((size_t)b * N + i0) * 64;
    const ushort* gh = gT_hi + ((size_t)b * N + j0) * 64;
    const ushort* gl = gT_lo + ((size_t)b * N + j0) * 64;
    #pragma unroll
    for (int v = tid; v < 1024; v += 256) {
        int row = v >> 3, ch = (v & 7) * 8;
        *(uint4*)&sm[0][row][ch] = *(const uint4*)&fh[(size_t)row * 64 + ch];
        *(uint4*)&sm[1][row][ch] = *(const uint4*)&fl[(size_t)row * 64 + ch];
        *(uint4*)&sm[2][row][ch] = *(const uint4*)&gh[(size_t)row * 64 + ch];
        *(uint4*)&sm[3][row][ch] = *(const uint4*)&gl[(size_t)row * 64 + ch];
    }
    __syncthreads();

    int w = tid >> 6, lane = tid & 63, l15 = lane & 15, quad = lane >> 4;
    f32x4 acc[2][8] = {};

    #pragma unroll
    for (int ks = 0; ks < 2; ++ks) {
        int kofs = ks * 32 + quad * 8;
        short8 a_hi[2], a_lo[2];
        #pragma unroll
        for (int tr = 0; tr < 2; ++tr) {
            a_hi[tr] = *(const short8*)&sm[0][w * 32 + tr * 16 + l15][kofs];
            a_lo[tr] = *(const short8*)&sm[1][w * 32 + tr * 16 + l15][kofs];
        }
        #pragma unroll
        for (int tc = 0; tc < 8; ++tc) {
            short8 b_hi = *(const short8*)&sm[2][tc * 16 + l15][kofs];
            short8 b_lo = *(const short8*)&sm[3][tc * 16 + l15][kofs];
            #pragma unroll
            for (int tr = 0; tr < 2; ++tr) {
                acc[tr][tc] = __builtin_amdgcn_mfma_f32_16x16x32_bf16(a_hi[tr], b_hi, acc[tr][tc], 0, 0, 0);
                acc[tr][tc] = __builtin_amdgcn_mfma_f32_16x16x32_bf16(a_hi[tr], b_lo, acc[tr][tc], 0, 0, 0);
                acc[tr][tc] = __builtin_amdgcn_mfma_f32_16x16x32_bf16(a_lo[tr], b_hi, acc[tr][tc], 0, 0, 0);
            }
        }
    }

    // exp, store unnormalized beta, per-thread colsum partials
    float cs[8];
    #pragma unroll
    for (int tc = 0; tc < 8; ++tc) cs[tc] = 0.f;
    float* pb = beta + (size_t)b * N * N;
    #pragma unroll
    for (int tr = 0; tr < 2; ++tr)
        #pragma unroll
        for (int tc = 0; tc < 8; ++tc) {
            int j = j0 + tc * 16 + l15;
            #pragma unroll
            for (int r = 0; r < 4; ++r) {
                int i = i0 + w * 32 + tr * 16 + quad * 4 + r;
                float v = __expf(acc[tr][tc][r] - 20.0f);
                cs[tc] += v;
                pb[(size_t)i * N + j] = v;
            }
        }

    // colsum reduction (verified round-1 pass-1 structure)
    __syncthreads();
    float* red = (float*)&sm[0][0][0];   // 128 j x 17 slots
    #pragma unroll
    for (int tc = 0; tc < 8; ++tc)
        red[(tc * 16 + l15) * 17 + (w * 4 + quad)] = cs[tc];
    __syncthreads();
    if (tid < 128) {
        float s = 0.f;
        #pragma unroll
        for (int sl = 0; sl < 16; ++sl) s += red[tid * 17 + sl];
        atomicAdd(&colsum[(size_t)b * N + j0 + tid], s);
    }
}

// ---------------------------------------------------------------------------
// Kernel 3: in-place invert colsum
// ---------------------------------------------------------------------------
__global__ __launch_bounds__(256)
void invert_colsum(float* __restrict__ c)
{
    int t = blockIdx.x * 256 + threadIdx.x;
    c[t] = 1.0f / c[t];
}

// ---------------------------------------------------------------------------
// Kernel 4: streaming normalize. One block per (b, row i):
// beta[b,i,j] *= inv_l[b,j]  (in place), rowsum[b,i] = sum_j beta.
// Fully coalesced, no atomics; inv_l row (16 KB) is L2-resident.
// ---------------------------------------------------------------------------
__global__ __launch_bounds__(256)
void normalize_rows(const float* __restrict__ inv_l, float* __restrict__ beta,
                    float* __restrict__ rowsum)
{
    int b = blockIdx.y, i = blockIdx.x, tid = threadIdx.x;
    float* row = beta + ((size_t)b * N + i) * N;
    const float* il = inv_l + (size_t)b * N;
    float s = 0.f;
    #pragma unroll
    for (int c = 0; c < 4; ++c) {
        int j = c * 1024 + tid * 4;
        float4 v = *(float4*)&row[j];
        float4 l = *(const float4*)&il[j];
        v.x *= l.x; v.y *= l.y; v.z *= l.z; v.w *= l.w;
        *(float4*)&row[j] = v;
        s += v.x + v.y + v.z + v.w;
    }
    #pragma unroll
    for (int off = 32; off > 0; off >>= 1) s += __shfl_down(s, off);
    __shared__ float wsum[4];
    if ((tid & 63) == 0) wsum[tid >> 6] = s;
    __syncthreads();
    if (tid == 0)
        rowsum[(size_t)b * N + i] = wsum[0] + wsum[1] + wsum[2] + wsum[3];
}

// ---------------------------------------------------------------------------
// Kernel 5: meanx[b,c] = mean_i x; t[b,c] = sum_i x[b,c,i]*rowsum[b,i]
// ---------------------------------------------------------------------------
__global__ __launch_bounds__(256)
void reduce_xr(const float* __restrict__ x, const float* __restrict__ rowsum,
               float* __restrict__ meanx, float* __restrict__ tvec)
{
    int b = blockIdx.y, c = blockIdx.x, tid = threadIdx.x;
    const float* xr = x + ((size_t)b * C + c) * N;
    const float* rr = rowsum + (size_t)b * N;
    float sx = 0.f, st = 0.f;
    for (int base = 0; base < N; base += 1024) {
        int i = base + tid * 4;
        float4 xv = *(const float4*)&xr[i];
        float4 rv = *(const float4*)&rr[i];
        sx += xv.x + xv.y + xv.z + xv.w;
        st += xv.x * rv.x + xv.y * rv.y + xv.z * rv.z + xv.w * rv.w;
    }
    __shared__ float s1[256], s2[256];
    s1[tid] = sx; s2[tid] = st;
    __syncthreads();
    for (int s = 128; s > 0; s >>= 1) {
        if (tid < s) { s1[tid] += s1[tid + s]; s2[tid] += s2[tid + s]; }
        __syncthreads();
    }
    if (tid == 0) {
        meanx[b * C + c] = s1[0] * (1.0f / N);
        tvec [b * C + c] = s2[0];
    }
}

// ---------------------------------------------------------------------------
// Kernel 6: pooled[b,c] = meanx + (gamma/N) * sum_c' Wv[c,c'] * t[b,c']
// ---------------------------------------------------------------------------
__global__ __launch_bounds__(64)
void pooled_out(const float* __restrict__ Wv, const float* __restrict__ meanx,
                const float* __restrict__ tvec, const float* __restrict__ gamma,
                float* __restrict__ out)
{
    int b = blockIdx.y, c = blockIdx.x;
    const float* wr = Wv + (size_t)c * C;
    const float* t  = tvec + (size_t)b * C;
    float s = 0.f;
    for (int cc = threadIdx.x; cc < C; cc += 64) s += wr[cc] * t[cc];
    for (int off = 32; off > 0; off >>= 1) s += __shfl_down(s, off);
    if (threadIdx.x == 0)
        out[b * C + c] = meanx[b * C + c] + gamma[0] * (1.0f / N) * s;
}

// ---------------------------------------------------------------------------
extern "C" void kernel_launch(void* const* d_in, const int* in_sizes, int n_in,
                              void* d_out, int out_size, void* d_ws, size_t ws_size,
                              hipStream_t stream)
{
    const float* x     = (const float*)d_in[0];
    const float* Wq    = (const float*)d_in[1];
    const float* Wk    = (const float*)d_in[2];
    const float* Wv    = (const float*)d_in[3];
    const float* gamma = (const float*)d_in[4];
    float* out  = (float*)d_out;
    float* beta = out + (size_t)B * C;

    ushort* fT_hi = (ushort*)d_ws;                         // each B*N*64 ushort
    ushort* fT_lo = fT_hi + (size_t)B * N * 64;
    ushort* gT_hi = fT_lo + (size_t)B * N * 64;
    ushort* gT_lo = gT_hi + (size_t)B * N * 64;
    float*  colsum = (float*)(gT_lo + (size_t)B * N * 64); // B*N
    float*  rowsum = colsum + (size_t)B * N;               // B*N
    float*  meanx  = rowsum + (size_t)B * N;               // B*C
    float*  tvec   = meanx + (size_t)B * C;                // B*C

    hipMemsetAsync(colsum, 0, (size_t)B * N * sizeof(float), stream);

    proj_fgT       <<<dim3(N / 64, B),           512, 0, stream>>>(x, Wq, Wk, fT_hi, fT_lo, gT_hi, gT_lo);
    scores_exp     <<<dim3(N / 128, N / 128, B), 256, 0, stream>>>(fT_hi, fT_lo, gT_hi, gT_lo,
                                                                   colsum, beta);
    invert_colsum  <<<dim3(B * N / 256),         256, 0, stream>>>(colsum);
    normalize_rows <<<dim3(N, B),                256, 0, stream>>>(colsum, beta, rowsum);
    reduce_xr      <<<dim3(C, B),                256, 0, stream>>>(x, rowsum, meanx, tvec);
    pooled_out     <<<dim3(C, B),                 64, 0, stream>>>(Wv, meanx, tvec, gamma, out);
}

// Round 6
// 410.693 us; speedup vs baseline: 1.2237x; 1.1352x over previous
//
#include <hip/hip_runtime.h>

constexpr int N  = 4096;   // H*W
constexpr int C  = 512;
constexpr int CK = 64;     // C/8
constexpr int B  = 4;

typedef __attribute__((ext_vector_type(8))) short short8;
typedef __attribute__((ext_vector_type(4))) float f32x4;

// ---------------------------------------------------------------------------
// Kernel 1 (fused): f = Wq @ x, g = Wk @ x in fp32, bf16 hi/lo split
// in-register, transposed through LDS, written as fT/gT [i][k] hi/lo.
// v2: 256 threads, 32-col tiles -> grid 512 = 2 blocks/CU (was 1),
// C-step 32 -> 32 barriers (was 64), float4 weight staging.
// Accumulation order over c unchanged -> bit-identical output.
// ---------------------------------------------------------------------------
__global__ __launch_bounds__(256, 2)
void proj_fgT(const float* __restrict__ x, const float* __restrict__ Wq,
              const float* __restrict__ Wk,
              ushort* __restrict__ fT_hi, ushort* __restrict__ fT_lo,
              ushort* __restrict__ gT_hi, ushort* __restrict__ gT_lo)
{
    int b  = blockIdx.y;
    int i0 = blockIdx.x * 32;
    __shared__ __align__(16) float  xs[32][36];    // pad 4 -> skew staging banks
    __shared__ __align__(16) float  ws[32][132];   // [cc][k-row]
    __shared__ __align__(16) ushort oh[32][136];   // [i][k] transposed out
    __shared__ __align__(16) ushort ol[32][136];
    int tid = threadIdx.x, ty = tid >> 3, tx = tid & 7;  // ty 0..31, tx 0..7
    float acc[4][4] = {};   // k = ty*4+r (0..127), i = i0 + tx*4+cl
    const float* xb = x + (size_t)b * C * N;

    for (int c0 = 0; c0 < C; c0 += 32) {
        {   // xs: 32 channels x 32 cols, one float4 per thread
            int cc = tid >> 3, col4 = (tid & 7) * 4;
            *(float4*)&xs[cc][col4] =
                *(const float4*)&xb[(size_t)(c0 + cc) * N + i0 + col4];
        }
        #pragma unroll
        for (int u = 0; u < 4; ++u) {   // ws: k-rows 0..127 x 32 channels
            int idx = tid + u * 256;    // row<64 <=> u<2 (wave-uniform branch)
            int row = idx >> 3, cc4 = (idx & 7) * 4;
            float4 wv = (row < 64)
                ? *(const float4*)&Wq[row * C + c0 + cc4]
                : *(const float4*)&Wk[(row - 64) * C + c0 + cc4];
            ws[cc4 + 0][row] = wv.x; ws[cc4 + 1][row] = wv.y;
            ws[cc4 + 2][row] = wv.z; ws[cc4 + 3][row] = wv.w;
        }
        __syncthreads();
        #pragma unroll
        for (int cc = 0; cc < 32; ++cc) {
            float4 wa = *(const float4*)&ws[cc][ty * 4];
            float4 xa = *(const float4*)&xs[cc][tx * 4];
            float wr[4] = {wa.x, wa.y, wa.z, wa.w};
            float xc[4] = {xa.x, xa.y, xa.z, xa.w};
            #pragma unroll
            for (int r = 0; r < 4; ++r)
                #pragma unroll
                for (int cl = 0; cl < 4; ++cl)
                    acc[r][cl] += wr[r] * xc[cl];
        }
        __syncthreads();
    }

    // in-register bf16 hi/lo split, transpose via LDS
    #pragma unroll
    for (int r = 0; r < 4; ++r)
        #pragma unroll
        for (int cl = 0; cl < 4; ++cl) {
            float v = acc[r][cl];
            unsigned bits = __float_as_uint(v);
            unsigned hb   = bits & 0xFFFF0000u;
            float lof = v - __uint_as_float(hb);
            oh[tx * 4 + cl][ty * 4 + r] = (ushort)(hb >> 16);
            ol[tx * 4 + cl][ty * 4 + r] = (ushort)(__float_as_uint(lof) >> 16);
        }
    __syncthreads();

    int i = tid >> 3, kc = (tid & 7) * 8;   // 32 i-rows x 8 k-chunks
    size_t ofs = ((size_t)b * N + i0 + i) * 64 + kc;
    *(uint4*)&fT_hi[ofs] = *(const uint4*)&oh[i][kc];
    *(uint4*)&fT_lo[ofs] = *(const uint4*)&ol[i][kc];
    *(uint4*)&gT_hi[ofs] = *(const uint4*)&oh[i][64 + kc];
    *(uint4*)&gT_lo[ofs] = *(const uint4*)&ol[i][64 + kc];
}

// ---------------------------------------------------------------------------
// Kernels 2/4: MFMA scores + exp (verified R1 structure). PASS=1: colsum
// only. PASS=2: write beta (scaled by inv colsum) + rowsum atomics.
// 128x128 tile, 4 waves, hi/lo split = 3 products, register-cached frags.
// ---------------------------------------------------------------------------
template <int PASS>
__global__ __launch_bounds__(256, 2)
void scores_pass(const ushort* __restrict__ fT_hi, const ushort* __restrict__ fT_lo,
                 const ushort* __restrict__ gT_hi, const ushort* __restrict__ gT_lo,
                 const float* __restrict__ inv_l, float* __restrict__ colsum,
                 float* __restrict__ beta, float* __restrict__ rowsum)
{
    int b = blockIdx.z, i0 = blockIdx.y * 128, j0 = blockIdx.x * 128;
    __shared__ ushort sm[4][128][72];   // 73.7 KB, pad 8 -> 2-way-free banks
    int tid = threadIdx.x;

    const ushort* fh = fT_hi + ((size_t)b * N + i0) * 64;
    const ushort* fl = fT_lo + ((size_t)b * N + i0) * 64;
    const ushort* gh = gT_hi + ((size_t)b * N + j0) * 64;
    const ushort* gl = gT_lo + ((size_t)b * N + j0) * 64;
    #pragma unroll
    for (int v = tid; v < 1024; v += 256) {
        int row = v >> 3, ch = (v & 7) * 8;
        *(uint4*)&sm[0][row][ch] = *(const uint4*)&fh[(size_t)row * 64 + ch];
        *(uint4*)&sm[1][row][ch] = *(const uint4*)&fl[(size_t)row * 64 + ch];
        *(uint4*)&sm[2][row][ch] = *(const uint4*)&gh[(size_t)row * 64 + ch];
        *(uint4*)&sm[3][row][ch] = *(const uint4*)&gl[(size_t)row * 64 + ch];
    }
    __syncthreads();

    int w = tid >> 6, lane = tid & 63, l15 = lane & 15, quad = lane >> 4;

    // PASS=2: issue inv_l loads early so latency hides under the MFMAs
    float il[8];
    if (PASS == 2) {
        #pragma unroll
        for (int tc = 0; tc < 8; ++tc)
            il[tc] = inv_l[(size_t)b * N + j0 + tc * 16 + l15];
    }

    f32x4 acc[2][8] = {};
    #pragma unroll
    for (int ks = 0; ks < 2; ++ks) {
        int kofs = ks * 32 + quad * 8;
        short8 a_hi[2], a_lo[2];
        #pragma unroll
        for (int tr = 0; tr < 2; ++tr) {
            a_hi[tr] = *(const short8*)&sm[0][w * 32 + tr * 16 + l15][kofs];
            a_lo[tr] = *(const short8*)&sm[1][w * 32 + tr * 16 + l15][kofs];
        }
        #pragma unroll
        for (int tc = 0; tc < 8; ++tc) {
            short8 b_hi = *(const short8*)&sm[2][tc * 16 + l15][kofs];
            short8 b_lo = *(const short8*)&sm[3][tc * 16 + l15][kofs];
            #pragma unroll
            for (int tr = 0; tr < 2; ++tr) {
                acc[tr][tc] = __builtin_amdgcn_mfma_f32_16x16x32_bf16(a_hi[tr], b_hi, acc[tr][tc], 0, 0, 0);
                acc[tr][tc] = __builtin_amdgcn_mfma_f32_16x16x32_bf16(a_hi[tr], b_lo, acc[tr][tc], 0, 0, 0);
                acc[tr][tc] = __builtin_amdgcn_mfma_f32_16x16x32_bf16(a_lo[tr], b_hi, acc[tr][tc], 0, 0, 0);
            }
        }
    }

    if (PASS == 1) {
        float cs[8];
        #pragma unroll
        for (int tc = 0; tc < 8; ++tc) cs[tc] = 0.f;
        #pragma unroll
        for (int tr = 0; tr < 2; ++tr)
            #pragma unroll
            for (int tc = 0; tc < 8; ++tc)
                #pragma unroll
                for (int r = 0; r < 4; ++r)
                    cs[tc] += __expf(acc[tr][tc][r] - 20.0f);
        __syncthreads();
        float* red = (float*)&sm[0][0][0];   // 128 j x 17 slots
        #pragma unroll
        for (int tc = 0; tc < 8; ++tc)
            red[(tc * 16 + l15) * 17 + (w * 4 + quad)] = cs[tc];
        __syncthreads();
        if (tid < 128) {
            float s = 0.f;
            #pragma unroll
            for (int sl = 0; sl < 16; ++sl) s += red[tid * 17 + sl];
            atomicAdd(&colsum[(size_t)b * N + j0 + tid], s);
        }
    } else {
        float* pb = beta + (size_t)b * N * N;
        #pragma unroll
        for (int tr = 0; tr < 2; ++tr) {
            float rp[4] = {0.f, 0.f, 0.f, 0.f};
            #pragma unroll
            for (int tc = 0; tc < 8; ++tc) {
                int j = j0 + tc * 16 + l15;
                #pragma unroll
                for (int r = 0; r < 4; ++r) {
                    int i = i0 + w * 32 + tr * 16 + quad * 4 + r;
                    float v = __expf(acc[tr][tc][r] - 20.0f) * il[tc];
                    rp[r] += v;
                    pb[(size_t)i * N + j] = v;
                }
            }
            #pragma unroll
            for (int r = 0; r < 4; ++r) {
                float s = rp[r];
                s += __shfl_xor(s, 1); s += __shfl_xor(s, 2);
                s += __shfl_xor(s, 4); s += __shfl_xor(s, 8);
                if (l15 == 0)
                    atomicAdd(&rowsum[(size_t)b * N + i0 + w * 32 + tr * 16 + quad * 4 + r], s);
            }
        }
    }
}

// ---------------------------------------------------------------------------
// Kernel 3: in-place invert colsum
// ---------------------------------------------------------------------------
__global__ __launch_bounds__(256)
void invert_colsum(float* __restrict__ c)
{
    int t = blockIdx.x * 256 + threadIdx.x;
    c[t] = 1.0f / c[t];
}

// ---------------------------------------------------------------------------
// Kernel 5: meanx[b,c] = mean_i x; t[b,c] = sum_i x[b,c,i]*rowsum[b,i]
// ---------------------------------------------------------------------------
__global__ __launch_bounds__(256)
void reduce_xr(const float* __restrict__ x, const float* __restrict__ rowsum,
               float* __restrict__ meanx, float* __restrict__ tvec)
{
    int b = blockIdx.y, c = blockIdx.x, tid = threadIdx.x;
    const float* xr = x + ((size_t)b * C + c) * N;
    const float* rr = rowsum + (size_t)b * N;
    float sx = 0.f, st = 0.f;
    for (int base = 0; base < N; base += 1024) {
        int i = base + tid * 4;
        float4 xv = *(const float4*)&xr[i];
        float4 rv = *(const float4*)&rr[i];
        sx += xv.x + xv.y + xv.z + xv.w;
        st += xv.x * rv.x + xv.y * rv.y + xv.z * rv.z + xv.w * rv.w;
    }
    __shared__ float s1[256], s2[256];
    s1[tid] = sx; s2[tid] = st;
    __syncthreads();
    for (int s = 128; s > 0; s >>= 1) {
        if (tid < s) { s1[tid] += s1[tid + s]; s2[tid] += s2[tid + s]; }
        __syncthreads();
    }
    if (tid == 0) {
        meanx[b * C + c] = s1[0] * (1.0f / N);
        tvec [b * C + c] = s2[0];
    }
}

// ---------------------------------------------------------------------------
// Kernel 6: pooled[b,c] = meanx + (gamma/N) * sum_c' Wv[c,c'] * t[b,c']
// ---------------------------------------------------------------------------
__global__ __launch_bounds__(64)
void pooled_out(const float* __restrict__ Wv, const float* __restrict__ meanx,
                const float* __restrict__ tvec, const float* __restrict__ gamma,
                float* __restrict__ out)
{
    int b = blockIdx.y, c = blockIdx.x;
    const float* wr = Wv + (size_t)c * C;
    const float* t  = tvec + (size_t)b * C;
    float s = 0.f;
    for (int cc = threadIdx.x; cc < C; cc += 64) s += wr[cc] * t[cc];
    for (int off = 32; off > 0; off >>= 1) s += __shfl_down(s, off);
    if (threadIdx.x == 0)
        out[b * C + c] = meanx[b * C + c] + gamma[0] * (1.0f / N) * s;
}

// ---------------------------------------------------------------------------
extern "C" void kernel_launch(void* const* d_in, const int* in_sizes, int n_in,
                              void* d_out, int out_size, void* d_ws, size_t ws_size,
                              hipStream_t stream)
{
    const float* x     = (const float*)d_in[0];
    const float* Wq    = (const float*)d_in[1];
    const float* Wk    = (const float*)d_in[2];
    const float* Wv    = (const float*)d_in[3];
    const float* gamma = (const float*)d_in[4];
    float* out  = (float*)d_out;
    float* beta = out + (size_t)B * C;

    ushort* fT_hi = (ushort*)d_ws;                         // each B*N*64 ushort
    ushort* fT_lo = fT_hi + (size_t)B * N * 64;
    ushort* gT_hi = fT_lo + (size_t)B * N * 64;
    ushort* gT_lo = gT_hi + (size_t)B * N * 64;
    float*  colsum = (float*)(gT_lo + (size_t)B * N * 64); // B*N
    float*  rowsum = colsum + (size_t)B * N;               // B*N
    float*  meanx  = rowsum + (size_t)B * N;               // B*C
    float*  tvec   = meanx + (size_t)B * C;                // B*C

    hipMemsetAsync(colsum, 0, 2 * (size_t)B * N * sizeof(float), stream);

    proj_fgT       <<<dim3(N / 32, B),           256, 0, stream>>>(x, Wq, Wk, fT_hi, fT_lo, gT_hi, gT_lo);
    scores_pass<1> <<<dim3(N / 128, N / 128, B), 256, 0, stream>>>(fT_hi, fT_lo, gT_hi, gT_lo,
                                                                   colsum, colsum, beta, rowsum);
    invert_colsum  <<<dim3(B * N / 256),         256, 0, stream>>>(colsum);
    scores_pass<2> <<<dim3(N / 128, N / 128, B), 256, 0, stream>>>(fT_hi, fT_lo, gT_hi, gT_lo,
                                                                   colsum, colsum, beta, rowsum);
    reduce_xr      <<<dim3(C, B),                256, 0, stream>>>(x, rowsum, meanx, tvec);
    pooled_out     <<<dim3(C, B),                 64, 0, stream>>>(Wv, meanx, tvec, gamma, out);
}